// Round 21
// baseline (79.530 us; speedup 1.0000x reference)
//
#include <hip/hip_runtime.h>

typedef unsigned short ushort_t;
typedef __attribute__((ext_vector_type(8))) short bf16x8;
typedef __attribute__((ext_vector_type(8))) unsigned short ushort8;
typedef __attribute__((ext_vector_type(4))) float f32x4;

__device__ __forceinline__ unsigned short f2bf(float f) {
  union { float f; unsigned u; } x; x.f = f;
  unsigned r = x.u + 0x7FFFu + ((x.u >> 16) & 1u);   // round-to-nearest-even
  return (unsigned short)(r >> 16);
}

// ---------------- fused chain: block = one o (512 blocks x 256 thr)
__global__ __launch_bounds__(256) void chain_kernel(const float* __restrict__ f0,
                                                    const float* __restrict__ f1,
                                                    const float* __restrict__ lf,
                                                    ushort_t* __restrict__ chainT) {
  __shared__ float gs[512];
  int o = blockIdx.x;
  int z = o & 7, y = (o >> 3) & 7, x = o >> 6;
  int tid = threadIdx.x;
  #pragma unroll
  for (int i = 0; i < 2; ++i) {
    int e = tid + i * 256;                 // (b*16+q)*4+c
    int c = e & 3, q = (e >> 2) & 15, b = e >> 6;
    float s = 0.f;
    #pragma unroll
    for (int r = 0; r < 16; ++r)
      s += f1[((b * 16 + q) * 16 + r) * 8 + y] * lf[(c * 16 + r) * 8 + z];
    gs[e] = s;
  }
  __syncthreads();
  #pragma unroll
  for (int j = 0; j < 4; ++j) {
    int k = tid + j * 256;
    int p = k & 3, c = (k >> 2) & 3, b = (k >> 4) & 7, a = k >> 7;
    float s = 0.f;
    #pragma unroll
    for (int q = 0; q < 16; ++q)
      s += f0[((a * 4 + p) * 16 + q) * 8 + x] * gs[(b * 16 + q) * 4 + c];
    chainT[(size_t)o * 1024 + k] = f2bf(s);
  }
}

// ---------------- depthwise 3x3 conv -> t[m][k] bf16 (K-contiguous)
// block = (n, h-oct: 8 out rows, 16-channel group). grid = 2048, 6 blocks/CU.
__global__ __launch_bounds__(256) void conv_kernel(const float* __restrict__ in,
                                                   const float* __restrict__ sf,
                                                   ushort_t* __restrict__ t) {
  __shared__ float in_lds[16][404];    // 16 ch x (10 rows * 40 + 4 pad)
  __shared__ float sf_l[36];
  int bid = blockIdx.x;
  int cg = bid & 15, hg = (bid >> 4) & 3, n = bid >> 6;
  int h0 = hg * 8;
  int tid = threadIdx.x;
  if (tid < 36) sf_l[tid] = sf[tid];
  for (int e = tid; e < 320; e += 256) {
    int ch = e / 20, rr = e % 20;
    in_lds[ch][(rr >> 1) * 40 + 3 + (rr & 1) * 33] = 0.f;
  }
  const float* inb = in + ((size_t)n * 256 + cg * 16) * 1024;
  #pragma unroll
  for (int i = 0; i < 5; ++i) {
    int e = tid + i * 256;
    int ch = e / 80, rem = e % 80;
    int r = rem >> 3, w4 = rem & 7;
    int hh = h0 - 1 + r;
    float4 v = make_float4(0.f, 0.f, 0.f, 0.f);
    if (hh >= 0 && hh < 32)
      v = *(const float4*)&inb[(size_t)ch * 1024 + hh * 32 + w4 * 4];
    *(float4*)&in_lds[ch][r * 40 + 4 + w4 * 4] = v;
  }
  __syncthreads();
  float sfr[36];
  #pragma unroll
  for (int i = 0; i < 36; ++i) sfr[i] = sf_l[i];
  int w = tid & 31, sub = tid >> 5;
  size_t m0 = (size_t)n * 1024 + (size_t)h0 * 32 + w;
  unsigned pw[8][4];
  #pragma unroll
  for (int b = 0; b < 2; ++b) {
    int ch = sub * 2 + b;
    float vals[10][3];
    #pragma unroll
    for (int r = 0; r < 10; ++r)
      #pragma unroll
      for (int dw = 0; dw < 3; ++dw)
        vals[r][dw] = in_lds[ch][r * 40 + 3 + w + dw];
    #pragma unroll
    for (int j = 0; j < 8; ++j) {
      float s0 = 0.f, s1 = 0.f, s2 = 0.f, s3 = 0.f;
      #pragma unroll
      for (int dr = 0; dr < 3; ++dr)
        #pragma unroll
        for (int dw = 0; dw < 3; ++dw) {
          float tv = vals[j + dr][dw];
          s0 += tv * sfr[0 * 9 + dr * 3 + dw];
          s1 += tv * sfr[1 * 9 + dr * 3 + dw];
          s2 += tv * sfr[2 * 9 + dr * 3 + dw];
          s3 += tv * sfr[3 * 9 + dr * 3 + dw];
        }
      pw[j][b * 2 + 0] = (unsigned)f2bf(s0) | ((unsigned)f2bf(s1) << 16);
      pw[j][b * 2 + 1] = (unsigned)f2bf(s2) | ((unsigned)f2bf(s3) << 16);
    }
  }
  #pragma unroll
  for (int j = 0; j < 8; ++j) {
    uint4 pk; pk.x = pw[j][0]; pk.y = pw[j][1]; pk.z = pw[j][2]; pk.w = pw[j][3];
    *(uint4*)&t[(m0 + (size_t)j * 32) * 1024 + (size_t)(cg * 64 + sub * 8)] = pk;
  }
}

// ---------------- GEMM: out[m][o] = sum_k t[m][k]*chainT[o][k] + bias[o]
// 128x128 tile, BK=32, triple-buffered ring (48 KB LDS) -> 3 blocks/CU.
// Grid 1024, 8 waves (4Mx2N -> per-wave 32x64). One barrier + producer-side
// VMCNT2 per kt; stage issued 2 kt ahead (ring mod 3).
// SWIZZLE (verified round 18, conflicts=0): 64B rows = 4 slots;
//   slot = kg ^ ((row>>1)&3); row bases mult of 16 -> (row>>1)&3 == (lr>>1)&3.
// (RAW) VMCNT2 at kt-end retires exactly kt+1's 2 loads (4 outstanding -> 2)
//   BEFORE the barrier releases readers. kt=30 uses VMCNT0.
// (WAR) stage(kt+2) targets buf[(kt-1)%3]; its reads were serviced (MFMA-
//   consumed + LGKMCNT0) before kt-1's closing barrier -- one barrier earlier.
#define AS1 __attribute__((address_space(1)))
#define AS3 __attribute__((address_space(3)))
#define BARRIER  __builtin_amdgcn_s_barrier()
#define LGKMCNT0 asm volatile("s_waitcnt lgkmcnt(0)" ::: "memory")
#define VMCNT2   asm volatile("s_waitcnt vmcnt(2)" ::: "memory")
#define VMCNT0   asm volatile("s_waitcnt vmcnt(0)" ::: "memory")

__global__ __launch_bounds__(512, 6) void gemm_kernel(const ushort_t* __restrict__ tA,
                                                      const ushort_t* __restrict__ tB,
                                                      const float* __restrict__ bias,
                                                      float* __restrict__ out) {
  __shared__ __align__(16) ushort_t As[3][4096];   // 3 x 8 KB: [128 rows][32 k] swizzled
  __shared__ __align__(16) ushort_t Bs[3][4096];   // 3 x 8 KB
  int tid = threadIdx.x;
  int bid = blockIdx.x;                            // 1024 blocks
  int wg = (bid & 7) * 128 + (bid >> 3);           // bijective XCD swizzle (1024%8==0)
  int tile_m = (wg >> 2) * 128;
  int tile_n = (wg & 3) * 128;

  int lane = tid & 63, wv = tid >> 6;
  int wm = (wv >> 1) * 32, wn = (wv & 1) * 64;     // per-wave 32M x 64N
  int lr = lane & 15, kg = lane >> 4;
  int kph = ((kg ^ ((lr >> 1) & 3)) * 8);          // verified slot function

  // staging: thread covers dest elems tid*8 (row = tid>>2, slot = tid&3);
  // source logical chunk = slot ^ ((row>>1)&3), pre-applied to global address.
  int srow = tid >> 2;                             // 0..127
  int lsw = (tid & 3) ^ ((srow >> 1) & 3);
  const ushort_t* sA = tA + (size_t)(tile_m + srow) * 1024 + lsw * 8;
  const ushort_t* sB = tB + (size_t)(tile_n + srow) * 1024 + lsw * 8;

#define STAGE(SB, KT)                                                                    \
  __builtin_amdgcn_global_load_lds((const AS1 void*)(sA + (KT) * 32),                    \
      (AS3 void*)&As[SB][tid * 8], 16, 0, 0);                                            \
  __builtin_amdgcn_global_load_lds((const AS1 void*)(sB + (KT) * 32),                    \
      (AS3 void*)&Bs[SB][tid * 8], 16, 0, 0);

#define COMPUTE(BUF)                                                                     \
  {                                                                                      \
    bf16x8 af[2], bq[4];                                                                 \
    af[0] = *(const bf16x8*)&As[BUF][(wm + lr) * 32 + kph];                              \
    af[1] = *(const bf16x8*)&As[BUF][(wm + 16 + lr) * 32 + kph];                         \
    _Pragma("unroll")                                                                    \
    for (int nf = 0; nf < 4; ++nf)                                                       \
      bq[nf] = *(const bf16x8*)&Bs[BUF][(wn + nf * 16 + lr) * 32 + kph];                 \
    __builtin_amdgcn_s_setprio(1);                                                       \
    _Pragma("unroll")                                                                    \
    for (int mf = 0; mf < 2; ++mf)                                                       \
      _Pragma("unroll")                                                                  \
      for (int nf = 0; nf < 4; ++nf)                                                     \
        acc[mf][nf] = __builtin_amdgcn_mfma_f32_16x16x32_bf16(                           \
            af[mf], bq[nf], acc[mf][nf], 0, 0, 0);                                       \
    __builtin_amdgcn_s_setprio(0);                                                       \
  }

  f32x4 acc[2][4];
  #pragma unroll
  for (int i = 0; i < 2; ++i)
    #pragma unroll
    for (int j = 0; j < 4; ++j) acc[i][j] = (f32x4){0.f, 0.f, 0.f, 0.f};

  // prologue: stage kt0->buf0, kt1->buf1 (4 loads); VMCNT2 certifies kt0
  // producer-side BEFORE the barrier (kt1's 2 stay in flight).
  STAGE(0, 0) STAGE(1, 1)
  VMCNT2; BARRIER;

  #pragma unroll 1
  for (int I = 0; I < 10; ++I) {
    int kt = 3 * I;
    STAGE(2, kt + 2)
    COMPUTE(0)
    LGKMCNT0; VMCNT2; BARRIER;
    STAGE(0, kt + 3)
    COMPUTE(1)
    LGKMCNT0; VMCNT2; BARRIER;
    STAGE(1, kt + 4)
    COMPUTE(2)
    LGKMCNT0; VMCNT2; BARRIER;
  }
  // kt=30 (buf0): no stage; certify kt31's loads fully.
  COMPUTE(0)
  VMCNT0; BARRIER;
  // kt=31 (buf1).
  COMPUTE(1)

  // epilogue: lane holds D[m=kg*4+r][o=lr] per 16x16 frag; bias L2-warm
  #pragma unroll
  for (int mf = 0; mf < 2; ++mf)
    #pragma unroll
    for (int nf = 0; nf < 4; ++nf) {
      int m = tile_m + wm + mf * 16 + kg * 4;
      int o = tile_n + wn + nf * 16 + lr;
      float bv = bias[o];
      f32x4 v = acc[mf][nf];
      v[0] += bv; v[1] += bv; v[2] += bv; v[3] += bv;
      *(f32x4*)&out[(size_t)(m >> 10) * 524288 + (size_t)o * 1024 + (size_t)(m & 1023)] = v;
    }
}

extern "C" void kernel_launch(void* const* d_in, const int* in_sizes, int n_in,
                              void* d_out, int out_size, void* d_ws, size_t ws_size,
                              hipStream_t stream) {
  (void)in_sizes; (void)n_in; (void)out_size; (void)ws_size;
  const float* in   = (const float*)d_in[0];
  const float* sf   = (const float*)d_in[1];
  const float* f0   = (const float*)d_in[2];
  const float* f1   = (const float*)d_in[3];
  const float* lf   = (const float*)d_in[4];
  const float* bias = (const float*)d_in[5];
  float* out = (float*)d_out;

  char* ws = (char*)d_ws;
  ushort_t* t      = (ushort_t*)ws;                          // 64 MB
  ushort_t* chainT = (ushort_t*)(ws + 67108864);             // 1 MB

  hipLaunchKernelGGL(chain_kernel, dim3(512),  dim3(256), 0, stream, f0, f1, lf, chainT);
  hipLaunchKernelGGL(conv_kernel,  dim3(2048), dim3(256), 0, stream, in, sf, t);
  hipLaunchKernelGGL(gemm_kernel,  dim3(1024), dim3(512), 0, stream, t, chainT, bias, out);
}

// Round 22
// 70.883 us; speedup vs baseline: 1.1220x; 1.1220x over previous
//
#include <hip/hip_runtime.h>

typedef unsigned short ushort_t;
typedef __attribute__((ext_vector_type(8))) short bf16x8;
typedef __attribute__((ext_vector_type(8))) unsigned short ushort8;
typedef __attribute__((ext_vector_type(4))) float f32x4;

__device__ __forceinline__ unsigned short f2bf(float f) {
  union { float f; unsigned u; } x; x.f = f;
  unsigned r = x.u + 0x7FFFu + ((x.u >> 16) & 1u);   // round-to-nearest-even
  return (unsigned short)(r >> 16);
}

// ---------------- fused chain: block = one o (512 blocks x 256 thr)
__global__ __launch_bounds__(256) void chain_kernel(const float* __restrict__ f0,
                                                    const float* __restrict__ f1,
                                                    const float* __restrict__ lf,
                                                    ushort_t* __restrict__ chainT) {
  __shared__ float gs[512];
  int o = blockIdx.x;
  int z = o & 7, y = (o >> 3) & 7, x = o >> 6;
  int tid = threadIdx.x;
  #pragma unroll
  for (int i = 0; i < 2; ++i) {
    int e = tid + i * 256;                 // (b*16+q)*4+c
    int c = e & 3, q = (e >> 2) & 15, b = e >> 6;
    float s = 0.f;
    #pragma unroll
    for (int r = 0; r < 16; ++r)
      s += f1[((b * 16 + q) * 16 + r) * 8 + y] * lf[(c * 16 + r) * 8 + z];
    gs[e] = s;
  }
  __syncthreads();
  #pragma unroll
  for (int j = 0; j < 4; ++j) {
    int k = tid + j * 256;
    int p = k & 3, c = (k >> 2) & 3, b = (k >> 4) & 7, a = k >> 7;
    float s = 0.f;
    #pragma unroll
    for (int q = 0; q < 16; ++q)
      s += f0[((a * 4 + p) * 16 + q) * 8 + x] * gs[(b * 16 + q) * 4 + c];
    chainT[(size_t)o * 1024 + k] = f2bf(s);
  }
}

// ---------------- depthwise 3x3 conv -> t[m][k] bf16 (K-contiguous)
// block = (n, h-oct: 8 out rows, 16-channel group). grid = 2048, 6 blocks/CU.
__global__ __launch_bounds__(256) void conv_kernel(const float* __restrict__ in,
                                                   const float* __restrict__ sf,
                                                   ushort_t* __restrict__ t) {
  __shared__ float in_lds[16][404];    // 16 ch x (10 rows * 40 + 4 pad)
  __shared__ float sf_l[36];
  int bid = blockIdx.x;
  int cg = bid & 15, hg = (bid >> 4) & 3, n = bid >> 6;
  int h0 = hg * 8;
  int tid = threadIdx.x;
  if (tid < 36) sf_l[tid] = sf[tid];
  for (int e = tid; e < 320; e += 256) {
    int ch = e / 20, rr = e % 20;
    in_lds[ch][(rr >> 1) * 40 + 3 + (rr & 1) * 33] = 0.f;
  }
  const float* inb = in + ((size_t)n * 256 + cg * 16) * 1024;
  #pragma unroll
  for (int i = 0; i < 5; ++i) {
    int e = tid + i * 256;
    int ch = e / 80, rem = e % 80;
    int r = rem >> 3, w4 = rem & 7;
    int hh = h0 - 1 + r;
    float4 v = make_float4(0.f, 0.f, 0.f, 0.f);
    if (hh >= 0 && hh < 32)
      v = *(const float4*)&inb[(size_t)ch * 1024 + hh * 32 + w4 * 4];
    *(float4*)&in_lds[ch][r * 40 + 4 + w4 * 4] = v;
  }
  __syncthreads();
  float sfr[36];
  #pragma unroll
  for (int i = 0; i < 36; ++i) sfr[i] = sf_l[i];
  int w = tid & 31, sub = tid >> 5;
  size_t m0 = (size_t)n * 1024 + (size_t)h0 * 32 + w;
  unsigned pw[8][4];
  #pragma unroll
  for (int b = 0; b < 2; ++b) {
    int ch = sub * 2 + b;
    float vals[10][3];
    #pragma unroll
    for (int r = 0; r < 10; ++r)
      #pragma unroll
      for (int dw = 0; dw < 3; ++dw)
        vals[r][dw] = in_lds[ch][r * 40 + 3 + w + dw];
    #pragma unroll
    for (int j = 0; j < 8; ++j) {
      float s0 = 0.f, s1 = 0.f, s2 = 0.f, s3 = 0.f;
      #pragma unroll
      for (int dr = 0; dr < 3; ++dr)
        #pragma unroll
        for (int dw = 0; dw < 3; ++dw) {
          float tv = vals[j + dr][dw];
          s0 += tv * sfr[0 * 9 + dr * 3 + dw];
          s1 += tv * sfr[1 * 9 + dr * 3 + dw];
          s2 += tv * sfr[2 * 9 + dr * 3 + dw];
          s3 += tv * sfr[3 * 9 + dr * 3 + dw];
        }
      pw[j][b * 2 + 0] = (unsigned)f2bf(s0) | ((unsigned)f2bf(s1) << 16);
      pw[j][b * 2 + 1] = (unsigned)f2bf(s2) | ((unsigned)f2bf(s3) << 16);
    }
  }
  #pragma unroll
  for (int j = 0; j < 8; ++j) {
    uint4 pk; pk.x = pw[j][0]; pk.y = pw[j][1]; pk.z = pw[j][2]; pk.w = pw[j][3];
    *(uint4*)&t[(m0 + (size_t)j * 32) * 1024 + (size_t)(cg * 64 + sub * 8)] = pk;
  }
}

// ---------------- GEMM: out[m][o] = sum_k t[m][k]*chainT[o][k] + bias[o]
// 128x128 tile, BK=64, 8 waves (4Mx2N -> per-wave 32x64), 64 KB LDS dbuf
// -> 2 blocks/CU, grid 1024. 8 single-barrier phases; producer-side VMCNT2.
// (Round-20 configuration — measured best: gemm ~45.9 us, total 70.54 us.)
#define AS1 __attribute__((address_space(1)))
#define AS3 __attribute__((address_space(3)))
#define BARRIER  __builtin_amdgcn_s_barrier()
#define LGKMCNT0 asm volatile("s_waitcnt lgkmcnt(0)" ::: "memory")
#define VMCNT2   asm volatile("s_waitcnt vmcnt(2)" ::: "memory")
#define VMCNT0   asm volatile("s_waitcnt vmcnt(0)" ::: "memory")

__global__ __launch_bounds__(512, 4) void gemm_kernel(const ushort_t* __restrict__ tA,
                                                      const ushort_t* __restrict__ tB,
                                                      const float* __restrict__ bias,
                                                      float* __restrict__ out) {
  __shared__ __align__(16) ushort_t smem[32768];   // 64 KB: As[2][8192] | Bs[2][8192]
  int tid = threadIdx.x;
  int bid = blockIdx.x;                            // 1024 blocks
  int wg = (bid & 7) * 128 + (bid >> 3);           // bijective XCD swizzle (1024%8==0)
  int tile_m = (wg >> 2) * 128;
  int tile_n = (wg & 3) * 128;

  int lane = tid & 63, wv = tid >> 6;
  int wm = (wv >> 1) * 32, wn = (wv & 1) * 64;     // per-wave 32M x 64N
  int lr = lane & 15, kg = lane >> 4;
  int kph0 = ((kg * 8) ^ ((lane & 7) * 8));
  int kph1 = ((32 + kg * 8) ^ ((lane & 7) * 8));
  int arow = wm + lr;
  int brow = wn + lr;

  int srow = tid >> 3;                             // 0..63 within a 64-row set
  int scol = ((tid & 7) ^ (srow & 7)) * 8;
  const ushort_t* sA = tA + (size_t)(tile_m + srow) * 1024 + scol;
  const ushort_t* sB = tB + (size_t)(tile_n + srow) * 1024 + scol;

#define STAGE_A(buf, koff, h)                                                                  \
  __builtin_amdgcn_global_load_lds((const AS1 void*)(sA + (size_t)((h)*64) * 1024 + (koff)),   \
      (AS3 void*)&smem[(buf)*8192 + (h)*4096 + tid*8], 16, 0, 0);
#define STAGE_B(buf, koff, h)                                                                  \
  __builtin_amdgcn_global_load_lds((const AS1 void*)(sB + (size_t)((h)*64) * 1024 + (koff)),   \
      (AS3 void*)&smem[16384 + (buf)*8192 + (h)*4096 + tid*8], 16, 0, 0);

#define READ_A1(dst, buf)                                                                      \
  dst[0] = *(const bf16x8*)&smem[(buf)*8192 + (arow)*64 + kph0];                               \
  dst[1] = *(const bf16x8*)&smem[(buf)*8192 + (arow)*64 + kph1];
#define READ_A2(dst, buf)                                                                      \
  dst[0] = *(const bf16x8*)&smem[(buf)*8192 + (arow + 16)*64 + kph0];                          \
  dst[1] = *(const bf16x8*)&smem[(buf)*8192 + (arow + 16)*64 + kph1];
#define READ_B(dst, nbase, buf)                                                                \
  _Pragma("unroll")                                                                            \
  for (int nf = 0; nf < 2; ++nf) {                                                             \
    dst[nf][0] = *(const bf16x8*)&smem[16384 + (buf)*8192 + (brow + (nbase) + nf*16)*64 + kph0];\
    dst[nf][1] = *(const bf16x8*)&smem[16384 + (buf)*8192 + (brow + (nbase) + nf*16)*64 + kph1];\
  }
#define Q_MFMA(AF, BF, MB, NB)                                                                 \
  __builtin_amdgcn_s_setprio(1);                                                              \
  _Pragma("unroll")                                                                            \
  for (int nf = 0; nf < 2; ++nf)                                                               \
    _Pragma("unroll")                                                                          \
    for (int ks = 0; ks < 2; ++ks)                                                             \
      acc[MB][(NB) + nf] = __builtin_amdgcn_mfma_f32_16x16x32_bf16(                            \
          AF[ks], BF[nf][ks], acc[MB][(NB) + nf], 0, 0, 0);                                    \
  __builtin_amdgcn_s_setprio(0);

  f32x4 acc[2][4];
  #pragma unroll
  for (int i = 0; i < 2; ++i)
    #pragma unroll
    for (int j = 0; j < 4; ++j) acc[i][j] = (f32x4){0.f, 0.f, 0.f, 0.f};

  bf16x8 a1[2], a2[2], b1[2][2], b2[2][2];

  // prologue: buf0 (kt0) 4 lines + A-buf1 (kt1) 2 lines; VMCNT2 retires buf0's 4
  // producer-side BEFORE the barrier releases readers (A-buf1's 2 stay in flight).
  STAGE_A(0, 0, 0) STAGE_A(0, 0, 1) STAGE_B(0, 0, 0) STAGE_B(0, 0, 1)
  STAGE_A(1, 64, 0) STAGE_A(1, 64, 1)
  VMCNT2; BARRIER;

#define ITER(I_, FULL)                                                                         \
  {                                                                                            \
    int k1 = (2*(I_)+1)*64, k2 = (2*(I_)+2)*64, k3 = (2*(I_)+3)*64;                            \
    /* p0: JIT reads a1,b1 (buf0); stage B1h1k1 */                                             \
    READ_A1(a1, 0) READ_B(b1, 0, 0)                                                            \
    STAGE_B(1, k1, 0)                                                                          \
    Q_MFMA(a1, b1, 0, 0) BARRIER;                                                              \
    /* p1: reads b2 (via MFMA), a2 (via LGKMCNT0); buf0 fully read after this */               \
    READ_B(b2, 32, 0) READ_A2(a2, 0)                                                           \
    STAGE_B(1, k1, 1)                                                                          \
    Q_MFMA(a1, b2, 0, 2) LGKMCNT0; BARRIER;                                                    \
    /* p2: A-buf0 re-stage safe */                                                             \
    if (FULL) { STAGE_A(0, k2, 0) }                                                            \
    Q_MFMA(a2, b2, 1, 2) BARRIER;                                                              \
    /* p3: certify buf1 DMA pre-close */                                                       \
    if (FULL) { STAGE_A(0, k2, 1) }                                                            \
    Q_MFMA(a2, b1, 1, 0)                                                                       \
    if (FULL) { VMCNT2; } else { VMCNT0; }                                                     \
    BARRIER;                                                                                   \
    /* p4: buf1 reads */                                                                       \
    READ_A1(a1, 1) READ_B(b1, 0, 1)                                                            \
    if (FULL) { STAGE_B(0, k2, 0) }                                                            \
    Q_MFMA(a1, b1, 0, 0) BARRIER;                                                              \
    /* p5 */                                                                                   \
    READ_B(b2, 32, 1) READ_A2(a2, 1)                                                           \
    if (FULL) { STAGE_B(0, k2, 1) }                                                            \
    Q_MFMA(a1, b2, 0, 2) LGKMCNT0; BARRIER;                                                    \
    /* p6 */                                                                                   \
    if (FULL) { STAGE_A(1, k3, 0) }                                                            \
    Q_MFMA(a2, b2, 1, 2) BARRIER;                                                              \
    /* p7: certify next buf0 DMA pre-close */                                                  \
    if (FULL) { STAGE_A(1, k3, 1) }                                                            \
    Q_MFMA(a2, b1, 1, 0)                                                                       \
    if (FULL) { VMCNT2; BARRIER; }                                                             \
  }

  for (int I = 0; I < 7; ++I) ITER(I, 1)
  ITER(7, 0)
#undef ITER

  // epilogue: lane holds D[m=kg*4+r][o=lr] per 16x16 frag; bias L2-warm
  #pragma unroll
  for (int mf = 0; mf < 2; ++mf)
    #pragma unroll
    for (int nf = 0; nf < 4; ++nf) {
      int m = tile_m + wm + mf * 16 + kg * 4;
      int o = tile_n + wn + nf * 16 + lr;
      float bv = bias[o];
      f32x4 v = acc[mf][nf];
      v[0] += bv; v[1] += bv; v[2] += bv; v[3] += bv;
      *(f32x4*)&out[(size_t)(m >> 10) * 524288 + (size_t)o * 1024 + (size_t)(m & 1023)] = v;
    }
}

extern "C" void kernel_launch(void* const* d_in, const int* in_sizes, int n_in,
                              void* d_out, int out_size, void* d_ws, size_t ws_size,
                              hipStream_t stream) {
  (void)in_sizes; (void)n_in; (void)out_size; (void)ws_size;
  const float* in   = (const float*)d_in[0];
  const float* sf   = (const float*)d_in[1];
  const float* f0   = (const float*)d_in[2];
  const float* f1   = (const float*)d_in[3];
  const float* lf   = (const float*)d_in[4];
  const float* bias = (const float*)d_in[5];
  float* out = (float*)d_out;

  char* ws = (char*)d_ws;
  ushort_t* t      = (ushort_t*)ws;                          // 64 MB
  ushort_t* chainT = (ushort_t*)(ws + 67108864);             // 1 MB

  hipLaunchKernelGGL(chain_kernel, dim3(512),  dim3(256), 0, stream, f0, f1, lf, chainT);
  hipLaunchKernelGGL(conv_kernel,  dim3(2048), dim3(256), 0, stream, in, sf, t);
  hipLaunchKernelGGL(gemm_kernel,  dim3(1024), dim3(512), 0, stream, t, chainT, bias, out);
}

// Round 23
// 69.222 us; speedup vs baseline: 1.1489x; 1.0240x over previous
//
#include <hip/hip_runtime.h>

typedef unsigned short ushort_t;
typedef __attribute__((ext_vector_type(8))) short bf16x8;
typedef __attribute__((ext_vector_type(8))) unsigned short ushort8;
typedef __attribute__((ext_vector_type(4))) float f32x4;

__device__ __forceinline__ unsigned short f2bf(float f) {
  union { float f; unsigned u; } x; x.f = f;
  unsigned r = x.u + 0x7FFFu + ((x.u >> 16) & 1u);   // round-to-nearest-even
  return (unsigned short)(r >> 16);
}

// ---------------- fused chain: block = one o (512 blocks x 256 thr)
__global__ __launch_bounds__(256) void chain_kernel(const float* __restrict__ f0,
                                                    const float* __restrict__ f1,
                                                    const float* __restrict__ lf,
                                                    ushort_t* __restrict__ chainT) {
  __shared__ float gs[512];
  int o = blockIdx.x;
  int z = o & 7, y = (o >> 3) & 7, x = o >> 6;
  int tid = threadIdx.x;
  #pragma unroll
  for (int i = 0; i < 2; ++i) {
    int e = tid + i * 256;                 // (b*16+q)*4+c
    int c = e & 3, q = (e >> 2) & 15, b = e >> 6;
    float s = 0.f;
    #pragma unroll
    for (int r = 0; r < 16; ++r)
      s += f1[((b * 16 + q) * 16 + r) * 8 + y] * lf[(c * 16 + r) * 8 + z];
    gs[e] = s;
  }
  __syncthreads();
  #pragma unroll
  for (int j = 0; j < 4; ++j) {
    int k = tid + j * 256;
    int p = k & 3, c = (k >> 2) & 3, b = (k >> 4) & 7, a = k >> 7;
    float s = 0.f;
    #pragma unroll
    for (int q = 0; q < 16; ++q)
      s += f0[((a * 4 + p) * 16 + q) * 8 + x] * gs[(b * 16 + q) * 4 + c];
    chainT[(size_t)o * 1024 + k] = f2bf(s);
  }
}

// ---------------- depthwise 3x3 conv -> t[m][k] bf16 (K-contiguous)
// block = (n, h-oct: 8 out rows, 16-channel group). grid = 2048, 6 blocks/CU.
__global__ __launch_bounds__(256) void conv_kernel(const float* __restrict__ in,
                                                   const float* __restrict__ sf,
                                                   ushort_t* __restrict__ t) {
  __shared__ float in_lds[16][404];    // 16 ch x (10 rows * 40 + 4 pad)
  __shared__ float sf_l[36];
  int bid = blockIdx.x;
  int cg = bid & 15, hg = (bid >> 4) & 3, n = bid >> 6;
  int h0 = hg * 8;
  int tid = threadIdx.x;
  if (tid < 36) sf_l[tid] = sf[tid];
  for (int e = tid; e < 320; e += 256) {
    int ch = e / 20, rr = e % 20;
    in_lds[ch][(rr >> 1) * 40 + 3 + (rr & 1) * 33] = 0.f;
  }
  const float* inb = in + ((size_t)n * 256 + cg * 16) * 1024;
  #pragma unroll
  for (int i = 0; i < 5; ++i) {
    int e = tid + i * 256;
    int ch = e / 80, rem = e % 80;
    int r = rem >> 3, w4 = rem & 7;
    int hh = h0 - 1 + r;
    float4 v = make_float4(0.f, 0.f, 0.f, 0.f);
    if (hh >= 0 && hh < 32)
      v = *(const float4*)&inb[(size_t)ch * 1024 + hh * 32 + w4 * 4];
    *(float4*)&in_lds[ch][r * 40 + 4 + w4 * 4] = v;
  }
  __syncthreads();
  float sfr[36];
  #pragma unroll
  for (int i = 0; i < 36; ++i) sfr[i] = sf_l[i];
  int w = tid & 31, sub = tid >> 5;
  size_t m0 = (size_t)n * 1024 + (size_t)h0 * 32 + w;
  unsigned pw[8][4];
  #pragma unroll
  for (int b = 0; b < 2; ++b) {
    int ch = sub * 2 + b;
    float vals[10][3];
    #pragma unroll
    for (int r = 0; r < 10; ++r)
      #pragma unroll
      for (int dw = 0; dw < 3; ++dw)
        vals[r][dw] = in_lds[ch][r * 40 + 3 + w + dw];
    #pragma unroll
    for (int j = 0; j < 8; ++j) {
      float s0 = 0.f, s1 = 0.f, s2 = 0.f, s3 = 0.f;
      #pragma unroll
      for (int dr = 0; dr < 3; ++dr)
        #pragma unroll
        for (int dw = 0; dw < 3; ++dw) {
          float tv = vals[j + dr][dw];
          s0 += tv * sfr[0 * 9 + dr * 3 + dw];
          s1 += tv * sfr[1 * 9 + dr * 3 + dw];
          s2 += tv * sfr[2 * 9 + dr * 3 + dw];
          s3 += tv * sfr[3 * 9 + dr * 3 + dw];
        }
      pw[j][b * 2 + 0] = (unsigned)f2bf(s0) | ((unsigned)f2bf(s1) << 16);
      pw[j][b * 2 + 1] = (unsigned)f2bf(s2) | ((unsigned)f2bf(s3) << 16);
    }
  }
  #pragma unroll
  for (int j = 0; j < 8; ++j) {
    uint4 pk; pk.x = pw[j][0]; pk.y = pw[j][1]; pk.z = pw[j][2]; pk.w = pw[j][3];
    *(uint4*)&t[(m0 + (size_t)j * 32) * 1024 + (size_t)(cg * 64 + sub * 8)] = pk;
  }
}

// ---------------- GEMM: out[m][o] = sum_k t[m][k]*chainT[o][k] + bias[o]
// 128x128 tile, BK=64, 4 waves (2Mx2N -> per-wave 64x64, reuse 4x4 ->
// 512 B LDS-read per MFMA, the binding resource), 64 KB LDS dbuf -> 2 blocks/CU,
// grid 1024. 8 single-barrier phases; producer-side counted VMCNT4.
// SYNC (r20 rules, re-traced):
//  (RAW) p3 FIFO [A1k3prev(4),B1k1(4),A0k2(4)] -> VMCNT4 retires buf1's 8;
//        p7 FIFO [A0k2(4),B0k2(4),A1k3(4)] -> retires buf0's 8. Tail: VMCNT0.
//  (WAR) buf reads end p1/p5 (a2/b2 forced by LGKMCNT0), re-stage >=1 barrier later.
#define AS1 __attribute__((address_space(1)))
#define AS3 __attribute__((address_space(3)))
#define BARRIER  __builtin_amdgcn_s_barrier()
#define LGKMCNT0 asm volatile("s_waitcnt lgkmcnt(0)" ::: "memory")
#define VMCNT4   asm volatile("s_waitcnt vmcnt(4)" ::: "memory")
#define VMCNT0   asm volatile("s_waitcnt vmcnt(0)" ::: "memory")

__global__ __launch_bounds__(256, 2) void gemm_kernel(const ushort_t* __restrict__ tA,
                                                      const ushort_t* __restrict__ tB,
                                                      const float* __restrict__ bias,
                                                      float* __restrict__ out) {
  __shared__ __align__(16) ushort_t smem[32768];   // 64 KB: As[2][8192] | Bs[2][8192]
  int tid = threadIdx.x;
  int bid = blockIdx.x;                            // 1024 blocks
  int wg = (bid & 7) * 128 + (bid >> 3);           // bijective XCD swizzle (1024%8==0)
  int tile_m = (wg >> 2) * 128;
  int tile_n = (wg & 3) * 128;

  int lane = tid & 63, wv = tid >> 6;              // 4 waves
  int wm = (wv >> 1) * 64, wn = (wv & 1) * 64;     // per-wave 64M x 64N
  int lr = lane & 15, kg = lane >> 4;
  int kph0 = ((kg * 8) ^ ((lane & 7) * 8));
  int kph1 = ((32 + kg * 8) ^ ((lane & 7) * 8));
  int arow = wm + lr;
  int brow = wn + lr;

  int srow = tid >> 3;                             // 0..31 (line covers 32 rows)
  int scol = ((tid & 7) ^ (srow & 7)) * 8;
  const ushort_t* sA = tA + (size_t)(tile_m + srow) * 1024 + scol;
  const ushort_t* sB = tB + (size_t)(tile_n + srow) * 1024 + scol;

#define STAGE_A(buf, koff, q)                                                                  \
  __builtin_amdgcn_global_load_lds((const AS1 void*)(sA + (size_t)((q)*32) * 1024 + (koff)),   \
      (AS3 void*)&smem[(buf)*8192 + (q)*2048 + tid*8], 16, 0, 0);
#define STAGE_B(buf, koff, q)                                                                  \
  __builtin_amdgcn_global_load_lds((const AS1 void*)(sB + (size_t)((q)*32) * 1024 + (koff)),   \
      (AS3 void*)&smem[16384 + (buf)*8192 + (q)*2048 + tid*8], 16, 0, 0);

#define READ_A1(dst, buf)                                                                      \
  _Pragma("unroll")                                                                            \
  for (int mf = 0; mf < 2; ++mf) {                                                             \
    dst[mf][0] = *(const bf16x8*)&smem[(buf)*8192 + (arow + mf*16)*64 + kph0];                 \
    dst[mf][1] = *(const bf16x8*)&smem[(buf)*8192 + (arow + mf*16)*64 + kph1];                 \
  }
#define READ_A2(dst, buf)                                                                      \
  _Pragma("unroll")                                                                            \
  for (int mf = 0; mf < 2; ++mf) {                                                             \
    dst[mf][0] = *(const bf16x8*)&smem[(buf)*8192 + (arow + 32 + mf*16)*64 + kph0];            \
    dst[mf][1] = *(const bf16x8*)&smem[(buf)*8192 + (arow + 32 + mf*16)*64 + kph1];            \
  }
#define READ_B1(dst, buf)                                                                      \
  _Pragma("unroll")                                                                            \
  for (int nf = 0; nf < 2; ++nf) {                                                             \
    dst[nf][0] = *(const bf16x8*)&smem[16384 + (buf)*8192 + (brow + nf*16)*64 + kph0];         \
    dst[nf][1] = *(const bf16x8*)&smem[16384 + (buf)*8192 + (brow + nf*16)*64 + kph1];         \
  }
#define READ_B2(dst, buf)                                                                      \
  _Pragma("unroll")                                                                            \
  for (int nf = 0; nf < 2; ++nf) {                                                             \
    dst[nf][0] = *(const bf16x8*)&smem[16384 + (buf)*8192 + (brow + 32 + nf*16)*64 + kph0];    \
    dst[nf][1] = *(const bf16x8*)&smem[16384 + (buf)*8192 + (brow + 32 + nf*16)*64 + kph1];    \
  }
#define Q_MFMA(AF, BF, MB, NB)                                                                 \
  __builtin_amdgcn_s_setprio(1);                                                              \
  _Pragma("unroll")                                                                            \
  for (int mf = 0; mf < 2; ++mf)                                                               \
    _Pragma("unroll")                                                                          \
    for (int nf = 0; nf < 2; ++nf)                                                             \
      _Pragma("unroll")                                                                        \
      for (int ks = 0; ks < 2; ++ks)                                                           \
        acc[(MB) + mf][(NB) + nf] = __builtin_amdgcn_mfma_f32_16x16x32_bf16(                   \
            AF[mf][ks], BF[nf][ks], acc[(MB) + mf][(NB) + nf], 0, 0, 0);                       \
  __builtin_amdgcn_s_setprio(0);

  f32x4 acc[4][4];
  #pragma unroll
  for (int i = 0; i < 4; ++i)
    #pragma unroll
    for (int j = 0; j < 4; ++j) acc[i][j] = (f32x4){0.f, 0.f, 0.f, 0.f};

  bf16x8 a1[2][2], a2[2][2], b1[2][2], b2[2][2];

  // prologue: buf0 (A 4 lines + B 4 lines) + A-buf1 (4 lines) = 12 loads;
  // VMCNT4 retires buf0's 8 producer-side, leaves A-buf1's 4 in flight.
  STAGE_A(0, 0, 0) STAGE_A(0, 0, 1) STAGE_A(0, 0, 2) STAGE_A(0, 0, 3)
  STAGE_B(0, 0, 0) STAGE_B(0, 0, 1) STAGE_B(0, 0, 2) STAGE_B(0, 0, 3)
  STAGE_A(1, 64, 0) STAGE_A(1, 64, 1) STAGE_A(1, 64, 2) STAGE_A(1, 64, 3)
  VMCNT4; BARRIER;

#define ITER(I_, FULL)                                                                         \
  {                                                                                            \
    int k1 = (2*(I_)+1)*64, k2 = (2*(I_)+2)*64, k3 = (2*(I_)+3)*64;                            \
    /* p0: reads a1,b1 (buf0); stage B1k1 q0,q1 */                                             \
    READ_A1(a1, 0) READ_B1(b1, 0)                                                              \
    STAGE_B(1, k1, 0) STAGE_B(1, k1, 1)                                                        \
    Q_MFMA(a1, b1, 0, 0) BARRIER;                                                              \
    /* p1: reads b2 (via MFMA), a2 (via LGKMCNT0); buf0 fully read after this */               \
    READ_B2(b2, 0) READ_A2(a2, 0)                                                              \
    STAGE_B(1, k1, 2) STAGE_B(1, k1, 3)                                                        \
    Q_MFMA(a1, b2, 0, 2) LGKMCNT0; BARRIER;                                                    \
    /* p2: A-buf0 re-stage safe */                                                             \
    if (FULL) { STAGE_A(0, k2, 0) STAGE_A(0, k2, 1) }                                          \
    Q_MFMA(a2, b2, 2, 2) BARRIER;                                                              \
    /* p3: certify buf1 DMA pre-close */                                                       \
    if (FULL) { STAGE_A(0, k2, 2) STAGE_A(0, k2, 3) }                                          \
    Q_MFMA(a2, b1, 2, 0)                                                                       \
    if (FULL) { VMCNT4; } else { VMCNT0; }                                                     \
    BARRIER;                                                                                   \
    /* p4: buf1 reads */                                                                       \
    READ_A1(a1, 1) READ_B1(b1, 1)                                                              \
    if (FULL) { STAGE_B(0, k2, 0) STAGE_B(0, k2, 1) }                                          \
    Q_MFMA(a1, b1, 0, 0) BARRIER;                                                              \
    /* p5 */                                                                                   \
    READ_B2(b2, 1) READ_A2(a2, 1)                                                              \
    if (FULL) { STAGE_B(0, k2, 2) STAGE_B(0, k2, 3) }                                          \
    Q_MFMA(a1, b2, 0, 2) LGKMCNT0; BARRIER;                                                    \
    /* p6 */                                                                                   \
    if (FULL) { STAGE_A(1, k3, 0) STAGE_A(1, k3, 1) }                                          \
    Q_MFMA(a2, b2, 2, 2) BARRIER;                                                              \
    /* p7: certify next buf0 DMA pre-close */                                                  \
    if (FULL) { STAGE_A(1, k3, 2) STAGE_A(1, k3, 3) }                                          \
    Q_MFMA(a2, b1, 2, 0)                                                                       \
    if (FULL) { VMCNT4; BARRIER; }                                                             \
  }

  for (int I = 0; I < 7; ++I) ITER(I, 1)
  ITER(7, 0)
#undef ITER

  // epilogue: lane holds D[m=kg*4+r][o=lr] per 16x16 frag; bias L2-warm
  #pragma unroll
  for (int mf = 0; mf < 4; ++mf)
    #pragma unroll
    for (int nf = 0; nf < 4; ++nf) {
      int m = tile_m + wm + mf * 16 + kg * 4;
      int o = tile_n + wn + nf * 16 + lr;
      float bv = bias[o];
      f32x4 v = acc[mf][nf];
      v[0] += bv; v[1] += bv; v[2] += bv; v[3] += bv;
      *(f32x4*)&out[(size_t)(m >> 10) * 524288 + (size_t)o * 1024 + (size_t)(m & 1023)] = v;
    }
}

extern "C" void kernel_launch(void* const* d_in, const int* in_sizes, int n_in,
                              void* d_out, int out_size, void* d_ws, size_t ws_size,
                              hipStream_t stream) {
  (void)in_sizes; (void)n_in; (void)out_size; (void)ws_size;
  const float* in   = (const float*)d_in[0];
  const float* sf   = (const float*)d_in[1];
  const float* f0   = (const float*)d_in[2];
  const float* f1   = (const float*)d_in[3];
  const float* lf   = (const float*)d_in[4];
  const float* bias = (const float*)d_in[5];
  float* out = (float*)d_out;

  char* ws = (char*)d_ws;
  ushort_t* t      = (ushort_t*)ws;                          // 64 MB
  ushort_t* chainT = (ushort_t*)(ws + 67108864);             // 1 MB

  hipLaunchKernelGGL(chain_kernel, dim3(512),  dim3(256), 0, stream, f0, f1, lf, chainT);
  hipLaunchKernelGGL(conv_kernel,  dim3(2048), dim3(256), 0, stream, in, sf, t);
  hipLaunchKernelGGL(gemm_kernel,  dim3(1024), dim3(256), 0, stream, t, chainT, bias, out);
}

// Round 24
// 67.241 us; speedup vs baseline: 1.1828x; 1.0295x over previous
//
#include <hip/hip_runtime.h>

typedef unsigned short ushort_t;
typedef __attribute__((ext_vector_type(8))) short bf16x8;
typedef __attribute__((ext_vector_type(8))) unsigned short ushort8;
typedef __attribute__((ext_vector_type(4))) float f32x4;

__device__ __forceinline__ unsigned short f2bf(float f) {
  union { float f; unsigned u; } x; x.f = f;
  unsigned r = x.u + 0x7FFFu + ((x.u >> 16) & 1u);   // round-to-nearest-even
  return (unsigned short)(r >> 16);
}

// ---------------- merged pre-kernel: blocks 0..511 = chain (one o each);
// blocks 512..2559 = depthwise conv (2048 blocks). Independent work, one launch.
__global__ __launch_bounds__(256) void pre_kernel(const float* __restrict__ f0,
                                                  const float* __restrict__ f1,
                                                  const float* __restrict__ lf,
                                                  ushort_t* __restrict__ chainT,
                                                  const float* __restrict__ in,
                                                  const float* __restrict__ sf,
                                                  ushort_t* __restrict__ t) {
  __shared__ __align__(16) char lds_raw[16 * 404 * 4 + 36 * 4];  // union: conv needs most
  int tid = threadIdx.x;

  if (blockIdx.x < 512) {
    // ---- chain: gs[b][q][c] then chainT[o][k]
    float* gs = (float*)lds_raw;                   // 512 floats
    int o = blockIdx.x;
    int z = o & 7, y = (o >> 3) & 7, x = o >> 6;
    #pragma unroll
    for (int i = 0; i < 2; ++i) {
      int e = tid + i * 256;                       // (b*16+q)*4+c
      int c = e & 3, q = (e >> 2) & 15, b = e >> 6;
      float s = 0.f;
      #pragma unroll
      for (int r = 0; r < 16; ++r)
        s += f1[((b * 16 + q) * 16 + r) * 8 + y] * lf[(c * 16 + r) * 8 + z];
      gs[e] = s;
    }
    __syncthreads();
    #pragma unroll
    for (int j = 0; j < 4; ++j) {
      int k = tid + j * 256;
      int p = k & 3, c = (k >> 2) & 3, b = (k >> 4) & 7, a = k >> 7;
      float s = 0.f;
      #pragma unroll
      for (int q = 0; q < 16; ++q)
        s += f0[((a * 4 + p) * 16 + q) * 8 + x] * gs[(b * 16 + q) * 4 + c];
      chainT[(size_t)o * 1024 + k] = f2bf(s);
    }
    return;
  }

  // ---- conv: block = (n, h-oct: 8 out rows, 16-channel group)
  float (*in_lds)[404] = (float (*)[404])lds_raw;  // 16 x 404 floats
  float* sf_l = (float*)(lds_raw + 16 * 404 * 4);  // 36 floats
  int bid = blockIdx.x - 512;
  int cg = bid & 15, hg = (bid >> 4) & 3, n = bid >> 6;
  int h0 = hg * 8;
  if (tid < 36) sf_l[tid] = sf[tid];
  for (int e = tid; e < 320; e += 256) {
    int ch = e / 20, rr = e % 20;
    in_lds[ch][(rr >> 1) * 40 + 3 + (rr & 1) * 33] = 0.f;
  }
  const float* inb = in + ((size_t)n * 256 + cg * 16) * 1024;
  #pragma unroll
  for (int i = 0; i < 5; ++i) {
    int e = tid + i * 256;
    int ch = e / 80, rem = e % 80;
    int r = rem >> 3, w4 = rem & 7;
    int hh = h0 - 1 + r;
    float4 v = make_float4(0.f, 0.f, 0.f, 0.f);
    if (hh >= 0 && hh < 32)
      v = *(const float4*)&inb[(size_t)ch * 1024 + hh * 32 + w4 * 4];
    *(float4*)&in_lds[ch][r * 40 + 4 + w4 * 4] = v;
  }
  __syncthreads();
  float sfr[36];
  #pragma unroll
  for (int i = 0; i < 36; ++i) sfr[i] = sf_l[i];
  int w = tid & 31, sub = tid >> 5;
  size_t m0 = (size_t)n * 1024 + (size_t)h0 * 32 + w;
  unsigned pw[8][4];
  #pragma unroll
  for (int b = 0; b < 2; ++b) {
    int ch = sub * 2 + b;
    float vals[10][3];
    #pragma unroll
    for (int r = 0; r < 10; ++r)
      #pragma unroll
      for (int dw = 0; dw < 3; ++dw)
        vals[r][dw] = in_lds[ch][r * 40 + 3 + w + dw];
    #pragma unroll
    for (int j = 0; j < 8; ++j) {
      float s0 = 0.f, s1 = 0.f, s2 = 0.f, s3 = 0.f;
      #pragma unroll
      for (int dr = 0; dr < 3; ++dr)
        #pragma unroll
        for (int dw = 0; dw < 3; ++dw) {
          float tv = vals[j + dr][dw];
          s0 += tv * sfr[0 * 9 + dr * 3 + dw];
          s1 += tv * sfr[1 * 9 + dr * 3 + dw];
          s2 += tv * sfr[2 * 9 + dr * 3 + dw];
          s3 += tv * sfr[3 * 9 + dr * 3 + dw];
        }
      pw[j][b * 2 + 0] = (unsigned)f2bf(s0) | ((unsigned)f2bf(s1) << 16);
      pw[j][b * 2 + 1] = (unsigned)f2bf(s2) | ((unsigned)f2bf(s3) << 16);
    }
  }
  #pragma unroll
  for (int j = 0; j < 8; ++j) {
    uint4 pk; pk.x = pw[j][0]; pk.y = pw[j][1]; pk.z = pw[j][2]; pk.w = pw[j][3];
    *(uint4*)&t[(m0 + (size_t)j * 32) * 1024 + (size_t)(cg * 64 + sub * 8)] = pk;
  }
}

// ---------------- GEMM: out[m][o] = sum_k t[m][k]*chainT[o][k] + bias[o]
// (verbatim round-23 best: 128x128 tile, BK=64, 4 waves 64x64/wave, 64 KB dbuf
//  -> 2 blocks/CU, 8 single-barrier phases, producer-side VMCNT4, XOR-swizzle.)
#define AS1 __attribute__((address_space(1)))
#define AS3 __attribute__((address_space(3)))
#define BARRIER  __builtin_amdgcn_s_barrier()
#define LGKMCNT0 asm volatile("s_waitcnt lgkmcnt(0)" ::: "memory")
#define VMCNT4   asm volatile("s_waitcnt vmcnt(4)" ::: "memory")
#define VMCNT0   asm volatile("s_waitcnt vmcnt(0)" ::: "memory")

__global__ __launch_bounds__(256, 2) void gemm_kernel(const ushort_t* __restrict__ tA,
                                                      const ushort_t* __restrict__ tB,
                                                      const float* __restrict__ bias,
                                                      float* __restrict__ out) {
  __shared__ __align__(16) ushort_t smem[32768];   // 64 KB: As[2][8192] | Bs[2][8192]
  int tid = threadIdx.x;
  int bid = blockIdx.x;                            // 1024 blocks
  int wg = (bid & 7) * 128 + (bid >> 3);           // bijective XCD swizzle (1024%8==0)
  int tile_m = (wg >> 2) * 128;
  int tile_n = (wg & 3) * 128;

  int lane = tid & 63, wv = tid >> 6;              // 4 waves
  int wm = (wv >> 1) * 64, wn = (wv & 1) * 64;     // per-wave 64M x 64N
  int lr = lane & 15, kg = lane >> 4;
  int kph0 = ((kg * 8) ^ ((lane & 7) * 8));
  int kph1 = ((32 + kg * 8) ^ ((lane & 7) * 8));
  int arow = wm + lr;
  int brow = wn + lr;

  int srow = tid >> 3;                             // 0..31 (line covers 32 rows)
  int scol = ((tid & 7) ^ (srow & 7)) * 8;
  const ushort_t* sA = tA + (size_t)(tile_m + srow) * 1024 + scol;
  const ushort_t* sB = tB + (size_t)(tile_n + srow) * 1024 + scol;

#define STAGE_A(buf, koff, q)                                                                  \
  __builtin_amdgcn_global_load_lds((const AS1 void*)(sA + (size_t)((q)*32) * 1024 + (koff)),   \
      (AS3 void*)&smem[(buf)*8192 + (q)*2048 + tid*8], 16, 0, 0);
#define STAGE_B(buf, koff, q)                                                                  \
  __builtin_amdgcn_global_load_lds((const AS1 void*)(sB + (size_t)((q)*32) * 1024 + (koff)),   \
      (AS3 void*)&smem[16384 + (buf)*8192 + (q)*2048 + tid*8], 16, 0, 0);

#define READ_A1(dst, buf)                                                                      \
  _Pragma("unroll")                                                                            \
  for (int mf = 0; mf < 2; ++mf) {                                                             \
    dst[mf][0] = *(const bf16x8*)&smem[(buf)*8192 + (arow + mf*16)*64 + kph0];                 \
    dst[mf][1] = *(const bf16x8*)&smem[(buf)*8192 + (arow + mf*16)*64 + kph1];                 \
  }
#define READ_A2(dst, buf)                                                                      \
  _Pragma("unroll")                                                                            \
  for (int mf = 0; mf < 2; ++mf) {                                                             \
    dst[mf][0] = *(const bf16x8*)&smem[(buf)*8192 + (arow + 32 + mf*16)*64 + kph0];            \
    dst[mf][1] = *(const bf16x8*)&smem[(buf)*8192 + (arow + 32 + mf*16)*64 + kph1];            \
  }
#define READ_B1(dst, buf)                                                                      \
  _Pragma("unroll")                                                                            \
  for (int nf = 0; nf < 2; ++nf) {                                                             \
    dst[nf][0] = *(const bf16x8*)&smem[16384 + (buf)*8192 + (brow + nf*16)*64 + kph0];         \
    dst[nf][1] = *(const bf16x8*)&smem[16384 + (buf)*8192 + (brow + nf*16)*64 + kph1];         \
  }
#define READ_B2(dst, buf)                                                                      \
  _Pragma("unroll")                                                                            \
  for (int nf = 0; nf < 2; ++nf) {                                                             \
    dst[nf][0] = *(const bf16x8*)&smem[16384 + (buf)*8192 + (brow + 32 + nf*16)*64 + kph0];    \
    dst[nf][1] = *(const bf16x8*)&smem[16384 + (buf)*8192 + (brow + 32 + nf*16)*64 + kph1];    \
  }
#define Q_MFMA(AF, BF, MB, NB)                                                                 \
  __builtin_amdgcn_s_setprio(1);                                                              \
  _Pragma("unroll")                                                                            \
  for (int mf = 0; mf < 2; ++mf)                                                               \
    _Pragma("unroll")                                                                          \
    for (int nf = 0; nf < 2; ++nf)                                                             \
      _Pragma("unroll")                                                                        \
      for (int ks = 0; ks < 2; ++ks)                                                           \
        acc[(MB) + mf][(NB) + nf] = __builtin_amdgcn_mfma_f32_16x16x32_bf16(                   \
            AF[mf][ks], BF[nf][ks], acc[(MB) + mf][(NB) + nf], 0, 0, 0);                       \
  __builtin_amdgcn_s_setprio(0);

  f32x4 acc[4][4];
  #pragma unroll
  for (int i = 0; i < 4; ++i)
    #pragma unroll
    for (int j = 0; j < 4; ++j) acc[i][j] = (f32x4){0.f, 0.f, 0.f, 0.f};

  bf16x8 a1[2][2], a2[2][2], b1[2][2], b2[2][2];

  STAGE_A(0, 0, 0) STAGE_A(0, 0, 1) STAGE_A(0, 0, 2) STAGE_A(0, 0, 3)
  STAGE_B(0, 0, 0) STAGE_B(0, 0, 1) STAGE_B(0, 0, 2) STAGE_B(0, 0, 3)
  STAGE_A(1, 64, 0) STAGE_A(1, 64, 1) STAGE_A(1, 64, 2) STAGE_A(1, 64, 3)
  VMCNT4; BARRIER;

#define ITER(I_, FULL)                                                                         \
  {                                                                                            \
    int k1 = (2*(I_)+1)*64, k2 = (2*(I_)+2)*64, k3 = (2*(I_)+3)*64;                            \
    READ_A1(a1, 0) READ_B1(b1, 0)                                                              \
    STAGE_B(1, k1, 0) STAGE_B(1, k1, 1)                                                        \
    Q_MFMA(a1, b1, 0, 0) BARRIER;                                                              \
    READ_B2(b2, 0) READ_A2(a2, 0)                                                              \
    STAGE_B(1, k1, 2) STAGE_B(1, k1, 3)                                                        \
    Q_MFMA(a1, b2, 0, 2) LGKMCNT0; BARRIER;                                                    \
    if (FULL) { STAGE_A(0, k2, 0) STAGE_A(0, k2, 1) }                                          \
    Q_MFMA(a2, b2, 2, 2) BARRIER;                                                              \
    if (FULL) { STAGE_A(0, k2, 2) STAGE_A(0, k2, 3) }                                          \
    Q_MFMA(a2, b1, 2, 0)                                                                       \
    if (FULL) { VMCNT4; } else { VMCNT0; }                                                     \
    BARRIER;                                                                                   \
    READ_A1(a1, 1) READ_B1(b1, 1)                                                              \
    if (FULL) { STAGE_B(0, k2, 0) STAGE_B(0, k2, 1) }                                          \
    Q_MFMA(a1, b1, 0, 0) BARRIER;                                                              \
    READ_B2(b2, 1) READ_A2(a2, 1)                                                              \
    if (FULL) { STAGE_B(0, k2, 2) STAGE_B(0, k2, 3) }                                          \
    Q_MFMA(a1, b2, 0, 2) LGKMCNT0; BARRIER;                                                    \
    if (FULL) { STAGE_A(1, k3, 0) STAGE_A(1, k3, 1) }                                          \
    Q_MFMA(a2, b2, 2, 2) BARRIER;                                                              \
    if (FULL) { STAGE_A(1, k3, 2) STAGE_A(1, k3, 3) }                                          \
    Q_MFMA(a2, b1, 2, 0)                                                                       \
    if (FULL) { VMCNT4; BARRIER; }                                                             \
  }

  for (int I = 0; I < 7; ++I) ITER(I, 1)
  ITER(7, 0)
#undef ITER

  // epilogue: lane holds D[m=kg*4+r][o=lr] per 16x16 frag; bias L2-warm
  #pragma unroll
  for (int mf = 0; mf < 4; ++mf)
    #pragma unroll
    for (int nf = 0; nf < 4; ++nf) {
      int m = tile_m + wm + mf * 16 + kg * 4;
      int o = tile_n + wn + nf * 16 + lr;
      float bv = bias[o];
      f32x4 v = acc[mf][nf];
      v[0] += bv; v[1] += bv; v[2] += bv; v[3] += bv;
      *(f32x4*)&out[(size_t)(m >> 10) * 524288 + (size_t)o * 1024 + (size_t)(m & 1023)] = v;
    }
}

extern "C" void kernel_launch(void* const* d_in, const int* in_sizes, int n_in,
                              void* d_out, int out_size, void* d_ws, size_t ws_size,
                              hipStream_t stream) {
  (void)in_sizes; (void)n_in; (void)out_size; (void)ws_size;
  const float* in   = (const float*)d_in[0];
  const float* sf   = (const float*)d_in[1];
  const float* f0   = (const float*)d_in[2];
  const float* f1   = (const float*)d_in[3];
  const float* lf   = (const float*)d_in[4];
  const float* bias = (const float*)d_in[5];
  float* out = (float*)d_out;

  char* ws = (char*)d_ws;
  ushort_t* t      = (ushort_t*)ws;                          // 64 MB
  ushort_t* chainT = (ushort_t*)(ws + 67108864);             // 1 MB

  hipLaunchKernelGGL(pre_kernel,  dim3(2560), dim3(256), 0, stream,
                     f0, f1, lf, chainT, in, sf, t);
  hipLaunchKernelGGL(gemm_kernel, dim3(1024), dim3(256), 0, stream, t, chainT, bias, out);
}

// Round 25
// 65.852 us; speedup vs baseline: 1.2077x; 1.0211x over previous
//
#include <hip/hip_runtime.h>

typedef unsigned short ushort_t;
typedef __attribute__((ext_vector_type(8))) short bf16x8;
typedef __attribute__((ext_vector_type(8))) unsigned short ushort8;
typedef __attribute__((ext_vector_type(4))) float f32x4;

__device__ __forceinline__ unsigned short f2bf(float f) {
  union { float f; unsigned u; } x; x.f = f;
  unsigned r = x.u + 0x7FFFu + ((x.u >> 16) & 1u);   // round-to-nearest-even
  return (unsigned short)(r >> 16);
}

// ---------------- merged pre-kernel: blocks 0..511 = chain (one o each);
// blocks 512..2559 = depthwise conv (2048 blocks). Independent work, one launch.
__global__ __launch_bounds__(256) void pre_kernel(const float* __restrict__ f0,
                                                  const float* __restrict__ f1,
                                                  const float* __restrict__ lf,
                                                  ushort_t* __restrict__ chainT,
                                                  const float* __restrict__ in,
                                                  const float* __restrict__ sf,
                                                  ushort_t* __restrict__ t) {
  __shared__ __align__(16) char lds_raw[16 * 404 * 4 + 36 * 4];  // union: conv needs most
  int tid = threadIdx.x;

  if (blockIdx.x < 512) {
    // ---- chain: gs[b][q][c] then chainT[o][k]
    float* gs = (float*)lds_raw;                   // 512 floats
    int o = blockIdx.x;
    int z = o & 7, y = (o >> 3) & 7, x = o >> 6;
    #pragma unroll
    for (int i = 0; i < 2; ++i) {
      int e = tid + i * 256;                       // (b*16+q)*4+c
      int c = e & 3, q = (e >> 2) & 15, b = e >> 6;
      float s = 0.f;
      #pragma unroll
      for (int r = 0; r < 16; ++r)
        s += f1[((b * 16 + q) * 16 + r) * 8 + y] * lf[(c * 16 + r) * 8 + z];
      gs[e] = s;
    }
    __syncthreads();
    #pragma unroll
    for (int j = 0; j < 4; ++j) {
      int k = tid + j * 256;
      int p = k & 3, c = (k >> 2) & 3, b = (k >> 4) & 7, a = k >> 7;
      float s = 0.f;
      #pragma unroll
      for (int q = 0; q < 16; ++q)
        s += f0[((a * 4 + p) * 16 + q) * 8 + x] * gs[(b * 16 + q) * 4 + c];
      chainT[(size_t)o * 1024 + k] = f2bf(s);
    }
    return;
  }

  // ---- conv: block = (n, h-oct: 8 out rows, 16-channel group)
  // LANE REMAP (r25): w = tid>>3, sub = tid&7 -> each 8-lane group writes one
  // pixel's full 128 B k-slice contiguously (8 x 128 B coalesced segments/wave).
  float (*in_lds)[404] = (float (*)[404])lds_raw;  // 16 x 404 floats
  float* sf_l = (float*)(lds_raw + 16 * 404 * 4);  // 36 floats
  int bid = blockIdx.x - 512;
  int cg = bid & 15, hg = (bid >> 4) & 3, n = bid >> 6;
  int h0 = hg * 8;
  if (tid < 36) sf_l[tid] = sf[tid];
  for (int e = tid; e < 320; e += 256) {
    int ch = e / 20, rr = e % 20;
    in_lds[ch][(rr >> 1) * 40 + 3 + (rr & 1) * 33] = 0.f;
  }
  const float* inb = in + ((size_t)n * 256 + cg * 16) * 1024;
  #pragma unroll
  for (int i = 0; i < 5; ++i) {
    int e = tid + i * 256;
    int ch = e / 80, rem = e % 80;
    int r = rem >> 3, w4 = rem & 7;
    int hh = h0 - 1 + r;
    float4 v = make_float4(0.f, 0.f, 0.f, 0.f);
    if (hh >= 0 && hh < 32)
      v = *(const float4*)&inb[(size_t)ch * 1024 + hh * 32 + w4 * 4];
    *(float4*)&in_lds[ch][r * 40 + 4 + w4 * 4] = v;
  }
  __syncthreads();
  float sfr[36];
  #pragma unroll
  for (int i = 0; i < 36; ++i) sfr[i] = sf_l[i];
  int w = tid >> 3, sub = tid & 7;                 // REMAPPED (was w=tid&31, sub=tid>>5)
  size_t m0 = (size_t)n * 1024 + (size_t)h0 * 32 + w;
  unsigned pw[8][4];
  #pragma unroll
  for (int b = 0; b < 2; ++b) {
    int ch = sub * 2 + b;
    float vals[10][3];
    #pragma unroll
    for (int r = 0; r < 10; ++r)
      #pragma unroll
      for (int dw = 0; dw < 3; ++dw)
        vals[r][dw] = in_lds[ch][r * 40 + 3 + w + dw];
    #pragma unroll
    for (int j = 0; j < 8; ++j) {
      float s0 = 0.f, s1 = 0.f, s2 = 0.f, s3 = 0.f;
      #pragma unroll
      for (int dr = 0; dr < 3; ++dr)
        #pragma unroll
        for (int dw = 0; dw < 3; ++dw) {
          float tv = vals[j + dr][dw];
          s0 += tv * sfr[0 * 9 + dr * 3 + dw];
          s1 += tv * sfr[1 * 9 + dr * 3 + dw];
          s2 += tv * sfr[2 * 9 + dr * 3 + dw];
          s3 += tv * sfr[3 * 9 + dr * 3 + dw];
        }
      pw[j][b * 2 + 0] = (unsigned)f2bf(s0) | ((unsigned)f2bf(s1) << 16);
      pw[j][b * 2 + 1] = (unsigned)f2bf(s2) | ((unsigned)f2bf(s3) << 16);
    }
  }
  #pragma unroll
  for (int j = 0; j < 8; ++j) {
    uint4 pk; pk.x = pw[j][0]; pk.y = pw[j][1]; pk.z = pw[j][2]; pk.w = pw[j][3];
    *(uint4*)&t[(m0 + (size_t)j * 32) * 1024 + (size_t)(cg * 64 + sub * 8)] = pk;
  }
}

// ---------------- GEMM: out[m][o] = sum_k t[m][k]*chainT[o][k] + bias[o]
// (verbatim round-23 best: 128x128 tile, BK=64, 4 waves 64x64/wave, 64 KB dbuf
//  -> 2 blocks/CU, 8 single-barrier phases, producer-side VMCNT4, XOR-swizzle.)
#define AS1 __attribute__((address_space(1)))
#define AS3 __attribute__((address_space(3)))
#define BARRIER  __builtin_amdgcn_s_barrier()
#define LGKMCNT0 asm volatile("s_waitcnt lgkmcnt(0)" ::: "memory")
#define VMCNT4   asm volatile("s_waitcnt vmcnt(4)" ::: "memory")
#define VMCNT0   asm volatile("s_waitcnt vmcnt(0)" ::: "memory")

__global__ __launch_bounds__(256, 2) void gemm_kernel(const ushort_t* __restrict__ tA,
                                                      const ushort_t* __restrict__ tB,
                                                      const float* __restrict__ bias,
                                                      float* __restrict__ out) {
  __shared__ __align__(16) ushort_t smem[32768];   // 64 KB: As[2][8192] | Bs[2][8192]
  int tid = threadIdx.x;
  int bid = blockIdx.x;                            // 1024 blocks
  int wg = (bid & 7) * 128 + (bid >> 3);           // bijective XCD swizzle (1024%8==0)
  int tile_m = (wg >> 2) * 128;
  int tile_n = (wg & 3) * 128;

  int lane = tid & 63, wv = tid >> 6;              // 4 waves
  int wm = (wv >> 1) * 64, wn = (wv & 1) * 64;     // per-wave 64M x 64N
  int lr = lane & 15, kg = lane >> 4;
  int kph0 = ((kg * 8) ^ ((lane & 7) * 8));
  int kph1 = ((32 + kg * 8) ^ ((lane & 7) * 8));
  int arow = wm + lr;
  int brow = wn + lr;

  int srow = tid >> 3;                             // 0..31 (line covers 32 rows)
  int scol = ((tid & 7) ^ (srow & 7)) * 8;
  const ushort_t* sA = tA + (size_t)(tile_m + srow) * 1024 + scol;
  const ushort_t* sB = tB + (size_t)(tile_n + srow) * 1024 + scol;

#define STAGE_A(buf, koff, q)                                                                  \
  __builtin_amdgcn_global_load_lds((const AS1 void*)(sA + (size_t)((q)*32) * 1024 + (koff)),   \
      (AS3 void*)&smem[(buf)*8192 + (q)*2048 + tid*8], 16, 0, 0);
#define STAGE_B(buf, koff, q)                                                                  \
  __builtin_amdgcn_global_load_lds((const AS1 void*)(sB + (size_t)((q)*32) * 1024 + (koff)),   \
      (AS3 void*)&smem[16384 + (buf)*8192 + (q)*2048 + tid*8], 16, 0, 0);

#define READ_A1(dst, buf)                                                                      \
  _Pragma("unroll")                                                                            \
  for (int mf = 0; mf < 2; ++mf) {                                                             \
    dst[mf][0] = *(const bf16x8*)&smem[(buf)*8192 + (arow + mf*16)*64 + kph0];                 \
    dst[mf][1] = *(const bf16x8*)&smem[(buf)*8192 + (arow + mf*16)*64 + kph1];                 \
  }
#define READ_A2(dst, buf)                                                                      \
  _Pragma("unroll")                                                                            \
  for (int mf = 0; mf < 2; ++mf) {                                                             \
    dst[mf][0] = *(const bf16x8*)&smem[(buf)*8192 + (arow + 32 + mf*16)*64 + kph0];            \
    dst[mf][1] = *(const bf16x8*)&smem[(buf)*8192 + (arow + 32 + mf*16)*64 + kph1];            \
  }
#define READ_B1(dst, buf)                                                                      \
  _Pragma("unroll")                                                                            \
  for (int nf = 0; nf < 2; ++nf) {                                                             \
    dst[nf][0] = *(const bf16x8*)&smem[16384 + (buf)*8192 + (brow + nf*16)*64 + kph0];         \
    dst[nf][1] = *(const bf16x8*)&smem[16384 + (buf)*8192 + (brow + nf*16)*64 + kph1];         \
  }
#define READ_B2(dst, buf)                                                                      \
  _Pragma("unroll")                                                                            \
  for (int nf = 0; nf < 2; ++nf) {                                                             \
    dst[nf][0] = *(const bf16x8*)&smem[16384 + (buf)*8192 + (brow + 32 + nf*16)*64 + kph0];    \
    dst[nf][1] = *(const bf16x8*)&smem[16384 + (buf)*8192 + (brow + 32 + nf*16)*64 + kph1];    \
  }
#define Q_MFMA(AF, BF, MB, NB)                                                                 \
  __builtin_amdgcn_s_setprio(1);                                                              \
  _Pragma("unroll")                                                                            \
  for (int mf = 0; mf < 2; ++mf)                                                               \
    _Pragma("unroll")                                                                          \
    for (int nf = 0; nf < 2; ++nf)                                                             \
      _Pragma("unroll")                                                                        \
      for (int ks = 0; ks < 2; ++ks)                                                           \
        acc[(MB) + mf][(NB) + nf] = __builtin_amdgcn_mfma_f32_16x16x32_bf16(                   \
            AF[mf][ks], BF[nf][ks], acc[(MB) + mf][(NB) + nf], 0, 0, 0);                       \
  __builtin_amdgcn_s_setprio(0);

  f32x4 acc[4][4];
  #pragma unroll
  for (int i = 0; i < 4; ++i)
    #pragma unroll
    for (int j = 0; j < 4; ++j) acc[i][j] = (f32x4){0.f, 0.f, 0.f, 0.f};

  bf16x8 a1[2][2], a2[2][2], b1[2][2], b2[2][2];

  STAGE_A(0, 0, 0) STAGE_A(0, 0, 1) STAGE_A(0, 0, 2) STAGE_A(0, 0, 3)
  STAGE_B(0, 0, 0) STAGE_B(0, 0, 1) STAGE_B(0, 0, 2) STAGE_B(0, 0, 3)
  STAGE_A(1, 64, 0) STAGE_A(1, 64, 1) STAGE_A(1, 64, 2) STAGE_A(1, 64, 3)
  VMCNT4; BARRIER;

#define ITER(I_, FULL)                                                                         \
  {                                                                                            \
    int k1 = (2*(I_)+1)*64, k2 = (2*(I_)+2)*64, k3 = (2*(I_)+3)*64;                            \
    READ_A1(a1, 0) READ_B1(b1, 0)                                                              \
    STAGE_B(1, k1, 0) STAGE_B(1, k1, 1)                                                        \
    Q_MFMA(a1, b1, 0, 0) BARRIER;                                                              \
    READ_B2(b2, 0) READ_A2(a2, 0)                                                              \
    STAGE_B(1, k1, 2) STAGE_B(1, k1, 3)                                                        \
    Q_MFMA(a1, b2, 0, 2) LGKMCNT0; BARRIER;                                                    \
    if (FULL) { STAGE_A(0, k2, 0) STAGE_A(0, k2, 1) }                                          \
    Q_MFMA(a2, b2, 2, 2) BARRIER;                                                              \
    if (FULL) { STAGE_A(0, k2, 2) STAGE_A(0, k2, 3) }                                          \
    Q_MFMA(a2, b1, 2, 0)                                                                       \
    if (FULL) { VMCNT4; } else { VMCNT0; }                                                     \
    BARRIER;                                                                                   \
    READ_A1(a1, 1) READ_B1(b1, 1)                                                              \
    if (FULL) { STAGE_B(0, k2, 0) STAGE_B(0, k2, 1) }                                          \
    Q_MFMA(a1, b1, 0, 0) BARRIER;                                                              \
    READ_B2(b2, 1) READ_A2(a2, 1)                                                              \
    if (FULL) { STAGE_B(0, k2, 2) STAGE_B(0, k2, 3) }                                          \
    Q_MFMA(a1, b2, 0, 2) LGKMCNT0; BARRIER;                                                    \
    if (FULL) { STAGE_A(1, k3, 0) STAGE_A(1, k3, 1) }                                          \
    Q_MFMA(a2, b2, 2, 2) BARRIER;                                                              \
    if (FULL) { STAGE_A(1, k3, 2) STAGE_A(1, k3, 3) }                                          \
    Q_MFMA(a2, b1, 2, 0)                                                                       \
    if (FULL) { VMCNT4; BARRIER; }                                                             \
  }

  for (int I = 0; I < 7; ++I) ITER(I, 1)
  ITER(7, 0)
#undef ITER

  // epilogue: lane holds D[m=kg*4+r][o=lr] per 16x16 frag; bias L2-warm
  #pragma unroll
  for (int mf = 0; mf < 4; ++mf)
    #pragma unroll
    for (int nf = 0; nf < 4; ++nf) {
      int m = tile_m + wm + mf * 16 + kg * 4;
      int o = tile_n + wn + nf * 16 + lr;
      float bv = bias[o];
      f32x4 v = acc[mf][nf];
      v[0] += bv; v[1] += bv; v[2] += bv; v[3] += bv;
      *(f32x4*)&out[(size_t)(m >> 10) * 524288 + (size_t)o * 1024 + (size_t)(m & 1023)] = v;
    }
}

extern "C" void kernel_launch(void* const* d_in, const int* in_sizes, int n_in,
                              void* d_out, int out_size, void* d_ws, size_t ws_size,
                              hipStream_t stream) {
  (void)in_sizes; (void)n_in; (void)out_size; (void)ws_size;
  const float* in   = (const float*)d_in[0];
  const float* sf   = (const float*)d_in[1];
  const float* f0   = (const float*)d_in[2];
  const float* f1   = (const float*)d_in[3];
  const float* lf   = (const float*)d_in[4];
  const float* bias = (const float*)d_in[5];
  float* out = (float*)d_out;

  char* ws = (char*)d_ws;
  ushort_t* t      = (ushort_t*)ws;                          // 64 MB
  ushort_t* chainT = (ushort_t*)(ws + 67108864);             // 1 MB

  hipLaunchKernelGGL(pre_kernel,  dim3(2560), dim3(256), 0, stream,
                     f0, f1, lf, chainT, in, sf, t);
  hipLaunchKernelGGL(gemm_kernel, dim3(1024), dim3(256), 0, stream, t, chainT, bias, out);
}